// Round 1
// baseline (579.588 us; speedup 1.0000x reference)
//
#include <hip/hip_runtime.h>
#include <hip/hip_bf16.h>

// Problem: SAGAN self-attention block, B=16, C=128, H=W=64.
// All inputs fp32 per reference. Output fp32 [16,128,64,64].
// ws layout (floats):
//   0       : Wn (theta 16x128, phi 16x128, g 64x128 contiguous = [96][128])
//   12288   : Wo_n [128][64]
//   20480   : theta [16][16][4096]
//   1069056 : phi   [16][16][1024]
//   1331200 : g     [16][64][1024]
//   2379776 : o     [16][64][4096]
// total 6,574,080 floats = 26.3 MB of ws.

#define WS_WN  0
#define WS_WO  12288
#define WS_TH  20480
#define WS_PHI 1069056
#define WS_G   1331200
#define WS_O   2379776

__device__ inline unsigned short f2b(float f) {
    union { float f; unsigned u; } v; v.f = f;
    unsigned r = v.u + 0x7FFFu + ((v.u >> 16) & 1u);   // RNE
    return (unsigned short)(r >> 16);
}
__device__ inline void unpack2(unsigned u, float& lo, float& hi) {
    union { unsigned u; float f; } a, b;
    a.u = u << 16; b.u = u & 0xFFFF0000u;
    lo = a.f; hi = b.f;
}

// ---------------- Kernel A: spectral norm (4 blocks, one per weight) --------
__global__ __launch_bounds__(256) void sn4(
        const float* __restrict__ w0, const float* __restrict__ w1,
        const float* __restrict__ w2, const float* __restrict__ w3,
        const float* __restrict__ u0, const float* __restrict__ u1,
        const float* __restrict__ u2, const float* __restrict__ u3,
        float* __restrict__ ws) {
    int wi = blockIdx.x;
    const float* W; const float* u; float* dst; int on, in_;
    if      (wi == 0) { W = w0; u = u0; dst = ws;          on = 16;  in_ = 128; }
    else if (wi == 1) { W = w1; u = u1; dst = ws + 2048;   on = 16;  in_ = 128; }
    else if (wi == 2) { W = w2; u = u2; dst = ws + 4096;   on = 64;  in_ = 128; }
    else              { W = w3; u = u3; dst = ws + 12288;  on = 128; in_ = 64;  }
    __shared__ float v[128];
    __shared__ float red[256];
    __shared__ float s_inv;
    int tid = threadIdx.x;
    // v_raw = u @ W
    float vi = 0.f;
    if (tid < in_) {
        for (int o = 0; o < on; ++o) vi += u[o] * W[o * in_ + tid];
    }
    red[tid] = (tid < in_) ? vi * vi : 0.f;
    __syncthreads();
    for (int st = 128; st > 0; st >>= 1) {
        if (tid < st) red[tid] += red[tid + st];
        __syncthreads();
    }
    float inv_nv = 1.0f / fmaxf(sqrtf(red[0]), 1e-12f);
    __syncthreads();
    if (tid < in_) v[tid] = vi * inv_nv;
    __syncthreads();
    // u2_raw = v @ W^T
    float ui = 0.f;
    if (tid < on) {
        for (int i = 0; i < in_; ++i) ui += v[i] * W[tid * in_ + i];
    }
    red[tid] = (tid < on) ? ui * ui : 0.f;
    __syncthreads();
    for (int st = 128; st > 0; st >>= 1) {
        if (tid < st) red[tid] += red[tid + st];
        __syncthreads();
    }
    if (tid == 0) {
        float nsq = red[0];
        float sv = nsq / fmaxf(sqrtf(nsq), 1e-12f);  // sv = ||u2_raw||
        s_inv = 1.0f / sv;
    }
    __syncthreads();
    float inv = s_inv;
    for (int e = tid; e < on * in_; e += 256) dst[e] = W[e] * inv;
}

// ------- Kernel B: theta/phi/g 1x1 conv + 2x2 maxpool (phi,g) ---------------
// grid: b*32 + rp (row-pair), 512 blocks, 256 threads.
__global__ __launch_bounds__(256) void convpool(
        const float* __restrict__ x, const float* __restrict__ wn,
        float* __restrict__ theta, float* __restrict__ phi, float* __restrict__ g) {
    __shared__ float wl[12288];   // [96][128]
    __shared__ float xs[2048];    // 16 c x 128 px chunk
    int tid = threadIdx.x;
    int b = blockIdx.x >> 5, rp = blockIdx.x & 31;
    const float4* w4 = (const float4*)wn;
    float4* wl4 = (float4*)wl;
    for (int i = tid; i < 3072; i += 256) wl4[i] = w4[i];
    int px4 = tid & 31;
    int ocg = (tid >> 5) * 12;
    float4 acc[12];
#pragma unroll
    for (int j = 0; j < 12; ++j) acc[j] = make_float4(0.f, 0.f, 0.f, 0.f);
    const float4* x4 = (const float4*)x;
    float4* xs4 = (float4*)xs;
    for (int cc = 0; cc < 128; cc += 16) {
        __syncthreads();
        for (int k = 0; k < 2; ++k) {
            int f = tid + k * 256;        // 512 float4 = 16c x 32px4
            int c = f >> 5, p = f & 31;
            xs4[c * 32 + p] = x4[(b * 128 + cc + c) * 1024 + rp * 32 + p];
        }
        __syncthreads();
#pragma unroll
        for (int c4 = 0; c4 < 4; ++c4) {
            float4 xv0 = xs4[(c4 * 4 + 0) * 32 + px4];
            float4 xv1 = xs4[(c4 * 4 + 1) * 32 + px4];
            float4 xv2 = xs4[(c4 * 4 + 2) * 32 + px4];
            float4 xv3 = xs4[(c4 * 4 + 3) * 32 + px4];
#pragma unroll
            for (int j = 0; j < 12; ++j) {
                float4 wv = wl4[(ocg + j) * 32 + (cc >> 2) + c4];
                acc[j].x += wv.x * xv0.x + wv.y * xv1.x + wv.z * xv2.x + wv.w * xv3.x;
                acc[j].y += wv.x * xv0.y + wv.y * xv1.y + wv.z * xv2.y + wv.w * xv3.y;
                acc[j].z += wv.x * xv0.z + wv.y * xv1.z + wv.z * xv2.z + wv.w * xv3.z;
                acc[j].w += wv.x * xv0.w + wv.y * xv1.w + wv.z * xv2.w + wv.w * xv3.w;
            }
        }
    }
    // epilogue
#pragma unroll
    for (int j = 0; j < 12; ++j) {
        int oc = ocg + j;
        if (oc < 16) {
            *(float4*)&theta[b * 65536 + oc * 4096 + rp * 128 + px4 * 4] = acc[j];
        } else {
            float m0 = fmaxf(acc[j].x, acc[j].y);
            float m1 = fmaxf(acc[j].z, acc[j].w);
            float o0 = fmaxf(m0, __shfl_xor(m0, 16));
            float o1 = fmaxf(m1, __shfl_xor(m1, 16));
            if (px4 < 16) {   // row 0 of the pair writes
                int t = rp * 32 + px4 * 2;
                float2 w2; w2.x = o0; w2.y = o1;
                if (oc < 32) *(float2*)&phi[b * 16384 + (oc - 16) * 1024 + t] = w2;
                else         *(float2*)&g[b * 65536 + (oc - 32) * 1024 + t] = w2;
            }
        }
    }
}

// ------- Kernel C: fused attention  o = softmax(theta^T phi) applied to g ----
// grid: b*64 + tile (64 s per tile), 1024 blocks, 256 threads.
__global__ __launch_bounds__(256) void attn(
        const float* __restrict__ theta, const float* __restrict__ phi,
        const float* __restrict__ g, float* __restrict__ o) {
    __shared__ unsigned short ph[16384];  // [16 c][1024 t] bf16
    __shared__ float th[1024];            // [16 c][64 s]
    __shared__ unsigned short ps[64 * 68];// chunk p  [t][s] bf16 (pad 68)
    __shared__ unsigned short gs[64 * 68];// chunk g  [t][c] bf16 (pad 68)
    __shared__ float sl[256];
    __shared__ float iL[64];
    int tid = threadIdx.x;
    int b = blockIdx.x >> 6, tile = blockIdx.x & 63;
    int s0 = tile << 6;
    for (int i = tid; i < 1024; i += 256) {
        int c = i >> 6, s = i & 63;
        th[i] = theta[b * 65536 + c * 4096 + s0 + s];
    }
    for (int i = tid; i < 16384; i += 256) {
        ph[i] = f2b(phi[b * 16384 + i]);
    }
    __syncthreads();
    int s = tid & 63, q = tid >> 6;
    float thc[16];
#pragma unroll
    for (int c = 0; c < 16; ++c) thc[c] = th[c * 64 + s];
    float l_part = 0.f;
    int sg = (tid & 15) * 4, cg = (tid >> 4) * 4;
    float a[16];
#pragma unroll
    for (int i = 0; i < 16; ++i) a[i] = 0.f;

    for (int tc = 0; tc < 16; ++tc) {
        int t0 = tc * 64;
        __syncthreads();   // previous chunk's PV done
        // stage g chunk (bf16, transposed to [t][c])
        for (int i = tid; i < 4096; i += 256) {
            int tl = i & 63, c = i >> 6;
            gs[tl * 68 + c] = f2b(g[b * 65536 + c * 1024 + t0 + tl]);
        }
        // compute p = exp(S) for 16 t per thread (this thread's s column)
        for (int i = 0; i < 16; i += 4) {
            int t = q * 16 + i;
            float S0 = 0.f, S1 = 0.f, S2 = 0.f, S3 = 0.f;
#pragma unroll
            for (int c = 0; c < 16; ++c) {
                uint2 pp = *(const uint2*)&ph[c * 1024 + t0 + t];
                float f0, f1, f2, f3;
                unpack2(pp.x, f0, f1); unpack2(pp.y, f2, f3);
                float tcv = thc[c];
                S0 += tcv * f0; S1 += tcv * f1; S2 += tcv * f2; S3 += tcv * f3;
            }
            float e0 = __expf(S0), e1 = __expf(S1), e2 = __expf(S2), e3 = __expf(S3);
            l_part += e0 + e1 + e2 + e3;
            ps[(t + 0) * 68 + s] = f2b(e0);
            ps[(t + 1) * 68 + s] = f2b(e1);
            ps[(t + 2) * 68 + s] = f2b(e2);
            ps[(t + 3) * 68 + s] = f2b(e3);
        }
        __syncthreads();
        // PV: 4x4 register tile (cg x sg)
        for (int t = 0; t < 64; ++t) {
            uint2 pv = *(const uint2*)&ps[t * 68 + sg];
            uint2 gv = *(const uint2*)&gs[t * 68 + cg];
            float p0, p1, p2, p3, g0, g1, g2, g3;
            unpack2(pv.x, p0, p1); unpack2(pv.y, p2, p3);
            unpack2(gv.x, g0, g1); unpack2(gv.y, g2, g3);
            a[0]  += g0 * p0; a[1]  += g0 * p1; a[2]  += g0 * p2; a[3]  += g0 * p3;
            a[4]  += g1 * p0; a[5]  += g1 * p1; a[6]  += g1 * p2; a[7]  += g1 * p3;
            a[8]  += g2 * p0; a[9]  += g2 * p1; a[10] += g2 * p2; a[11] += g2 * p3;
            a[12] += g3 * p0; a[13] += g3 * p1; a[14] += g3 * p2; a[15] += g3 * p3;
        }
    }
    // combine softmax denominators (deferred normalization)
    sl[q * 64 + s] = l_part;
    __syncthreads();
    if (tid < 64) iL[tid] = 1.0f / (sl[tid] + sl[64 + tid] + sl[128 + tid] + sl[192 + tid]);
    __syncthreads();
    float il0 = iL[sg], il1 = iL[sg + 1], il2 = iL[sg + 2], il3 = iL[sg + 3];
#pragma unroll
    for (int ci = 0; ci < 4; ++ci) {
        float4 r;
        r.x = a[ci * 4 + 0] * il0;
        r.y = a[ci * 4 + 1] * il1;
        r.z = a[ci * 4 + 2] * il2;
        r.w = a[ci * 4 + 3] * il3;
        *(float4*)&o[b * 262144 + (cg + ci) * 4096 + s0 + sg] = r;
    }
}

// ------- Kernel D: out = gamma * (Wo @ o) + x --------------------------------
// grid: b*32 + pt (128-px tile), 512 blocks, 256 threads.
__global__ __launch_bounds__(256) void outconv(
        const float* __restrict__ o, const float* __restrict__ won,
        const float* __restrict__ x, const float* __restrict__ gam,
        float* __restrict__ out) {
    __shared__ float wol[8192];   // [128 oc][64 c]
    __shared__ float ot[4096];    // 32 c x 128 px chunk
    int tid = threadIdx.x;
    int b = blockIdx.x >> 5, pt = blockIdx.x & 31;
    float4* wol4 = (float4*)wol;
    float4* ot4 = (float4*)ot;
    for (int i = tid; i < 2048; i += 256) wol4[i] = ((const float4*)won)[i];
    int px4 = tid & 31, og = (tid >> 5) * 16;
    float4 acc[16];
#pragma unroll
    for (int j = 0; j < 16; ++j) acc[j] = make_float4(0.f, 0.f, 0.f, 0.f);
    for (int cc = 0; cc < 64; cc += 32) {
        __syncthreads();
        for (int k = 0; k < 4; ++k) {
            int f = tid + k * 256;         // 1024 float4 = 32c x 32px4
            int c = f >> 5, p = f & 31;
            ot4[c * 32 + p] = ((const float4*)o)[(b * 64 + cc + c) * 1024 + pt * 32 + p];
        }
        __syncthreads();
#pragma unroll
        for (int c4 = 0; c4 < 8; ++c4) {
            float4 ov0 = ot4[(c4 * 4 + 0) * 32 + px4];
            float4 ov1 = ot4[(c4 * 4 + 1) * 32 + px4];
            float4 ov2 = ot4[(c4 * 4 + 2) * 32 + px4];
            float4 ov3 = ot4[(c4 * 4 + 3) * 32 + px4];
#pragma unroll
            for (int j = 0; j < 16; ++j) {
                float4 wv = wol4[(og + j) * 16 + (cc >> 2) + c4];
                acc[j].x += wv.x * ov0.x + wv.y * ov1.x + wv.z * ov2.x + wv.w * ov3.x;
                acc[j].y += wv.x * ov0.y + wv.y * ov1.y + wv.z * ov2.y + wv.w * ov3.y;
                acc[j].z += wv.x * ov0.z + wv.y * ov1.z + wv.z * ov2.z + wv.w * ov3.z;
                acc[j].w += wv.x * ov0.w + wv.y * ov1.w + wv.z * ov2.w + wv.w * ov3.w;
            }
        }
    }
    float gm = gam[0];
#pragma unroll
    for (int j = 0; j < 16; ++j) {
        int oc = og + j;
        int gi = (b * 128 + oc) * 1024 + pt * 32 + px4;   // float4 index
        float4 xv = ((const float4*)x)[gi];
        float4 r;
        r.x = gm * acc[j].x + xv.x;
        r.y = gm * acc[j].y + xv.y;
        r.z = gm * acc[j].z + xv.z;
        r.w = gm * acc[j].w + xv.w;
        ((float4*)out)[gi] = r;
    }
}

extern "C" void kernel_launch(void* const* d_in, const int* in_sizes, int n_in,
                              void* d_out, int out_size, void* d_ws, size_t ws_size,
                              hipStream_t stream) {
    const float* x  = (const float*)d_in[0];
    const float* wt = (const float*)d_in[1];
    const float* wp = (const float*)d_in[2];
    const float* wg = (const float*)d_in[3];
    const float* wo = (const float*)d_in[4];
    const float* ut = (const float*)d_in[5];
    const float* up = (const float*)d_in[6];
    const float* ug = (const float*)d_in[7];
    const float* uo = (const float*)d_in[8];
    const float* gm = (const float*)d_in[9];
    float* ws = (float*)d_ws;
    float* out = (float*)d_out;

    sn4<<<4, 256, 0, stream>>>(wt, wp, wg, wo, ut, up, ug, uo, ws);
    convpool<<<512, 256, 0, stream>>>(x, ws + WS_WN,
                                      ws + WS_TH, ws + WS_PHI, ws + WS_G);
    attn<<<1024, 256, 0, stream>>>(ws + WS_TH, ws + WS_PHI, ws + WS_G, ws + WS_O);
    outconv<<<512, 256, 0, stream>>>(ws + WS_O, ws + WS_WO, x, gm, out);
}

// Round 2
// 356.380 us; speedup vs baseline: 1.6263x; 1.6263x over previous
//
#include <hip/hip_runtime.h>
#include <hip/hip_bf16.h>

// Problem: SAGAN self-attention block, B=16, C=128, H=W=64.
// All inputs fp32 per reference. Output fp32 [16,128,64,64].
// ws layout (floats):
//   0       : Wn (theta 16x128, phi 16x128, g 64x128 contiguous = [96][128])
//   12288   : Wo_n [128][64]
//   20480   : theta [16][16][4096]
//   1069056 : phi   [16][16][1024]
//   1331200 : g     [16][64][1024]
//   2379776 : o     [16][64][4096]

#define WS_WN  0
#define WS_WO  12288
#define WS_TH  20480
#define WS_PHI 1069056
#define WS_G   1331200
#define WS_O   2379776

typedef __attribute__((ext_vector_type(8))) short bf16x8;
typedef __attribute__((ext_vector_type(4))) float f32x4;

__device__ inline unsigned short f2b(float f) {
    union { float f; unsigned u; } v; v.f = f;
    unsigned r = v.u + 0x7FFFu + ((v.u >> 16) & 1u);   // RNE
    return (unsigned short)(r >> 16);
}

// ---------------- Kernel A: spectral norm (4 blocks, one per weight) --------
__global__ __launch_bounds__(256) void sn4(
        const float* __restrict__ w0, const float* __restrict__ w1,
        const float* __restrict__ w2, const float* __restrict__ w3,
        const float* __restrict__ u0, const float* __restrict__ u1,
        const float* __restrict__ u2, const float* __restrict__ u3,
        float* __restrict__ ws) {
    int wi = blockIdx.x;
    const float* W; const float* u; float* dst; int on, in_;
    if      (wi == 0) { W = w0; u = u0; dst = ws;          on = 16;  in_ = 128; }
    else if (wi == 1) { W = w1; u = u1; dst = ws + 2048;   on = 16;  in_ = 128; }
    else if (wi == 2) { W = w2; u = u2; dst = ws + 4096;   on = 64;  in_ = 128; }
    else              { W = w3; u = u3; dst = ws + 12288;  on = 128; in_ = 64;  }
    __shared__ float v[128];
    __shared__ float red[256];
    __shared__ float s_inv;
    int tid = threadIdx.x;
    float vi = 0.f;
    if (tid < in_) {
        for (int o = 0; o < on; ++o) vi += u[o] * W[o * in_ + tid];
    }
    red[tid] = (tid < in_) ? vi * vi : 0.f;
    __syncthreads();
    for (int st = 128; st > 0; st >>= 1) {
        if (tid < st) red[tid] += red[tid + st];
        __syncthreads();
    }
    float inv_nv = 1.0f / fmaxf(sqrtf(red[0]), 1e-12f);
    __syncthreads();
    if (tid < in_) v[tid] = vi * inv_nv;
    __syncthreads();
    float ui = 0.f;
    if (tid < on) {
        for (int i = 0; i < in_; ++i) ui += v[i] * W[tid * in_ + i];
    }
    red[tid] = (tid < on) ? ui * ui : 0.f;
    __syncthreads();
    for (int st = 128; st > 0; st >>= 1) {
        if (tid < st) red[tid] += red[tid + st];
        __syncthreads();
    }
    if (tid == 0) {
        float nsq = red[0];
        float sv = nsq / fmaxf(sqrtf(nsq), 1e-12f);
        s_inv = 1.0f / sv;
    }
    __syncthreads();
    float inv = s_inv;
    for (int e = tid; e < on * in_; e += 256) dst[e] = W[e] * inv;
}

// ------- Kernel B: theta/phi/g 1x1 conv + 2x2 maxpool (phi,g) ---------------
__global__ __launch_bounds__(256) void convpool(
        const float* __restrict__ x, const float* __restrict__ wn,
        float* __restrict__ theta, float* __restrict__ phi, float* __restrict__ g) {
    __shared__ float wl[12288];   // [96][128]
    __shared__ float xs[2048];    // 16 c x 128 px chunk
    int tid = threadIdx.x;
    int b = blockIdx.x >> 5, rp = blockIdx.x & 31;
    const float4* w4 = (const float4*)wn;
    float4* wl4 = (float4*)wl;
    for (int i = tid; i < 3072; i += 256) wl4[i] = w4[i];
    int px4 = tid & 31;
    int ocg = (tid >> 5) * 12;
    float4 acc[12];
#pragma unroll
    for (int j = 0; j < 12; ++j) acc[j] = make_float4(0.f, 0.f, 0.f, 0.f);
    const float4* x4 = (const float4*)x;
    float4* xs4 = (float4*)xs;
    for (int cc = 0; cc < 128; cc += 16) {
        __syncthreads();
        for (int k = 0; k < 2; ++k) {
            int f = tid + k * 256;
            int c = f >> 5, p = f & 31;
            xs4[c * 32 + p] = x4[(b * 128 + cc + c) * 1024 + rp * 32 + p];
        }
        __syncthreads();
#pragma unroll
        for (int c4 = 0; c4 < 4; ++c4) {
            float4 xv0 = xs4[(c4 * 4 + 0) * 32 + px4];
            float4 xv1 = xs4[(c4 * 4 + 1) * 32 + px4];
            float4 xv2 = xs4[(c4 * 4 + 2) * 32 + px4];
            float4 xv3 = xs4[(c4 * 4 + 3) * 32 + px4];
#pragma unroll
            for (int j = 0; j < 12; ++j) {
                float4 wv = wl4[(ocg + j) * 32 + (cc >> 2) + c4];
                acc[j].x += wv.x * xv0.x + wv.y * xv1.x + wv.z * xv2.x + wv.w * xv3.x;
                acc[j].y += wv.x * xv0.y + wv.y * xv1.y + wv.z * xv2.y + wv.w * xv3.y;
                acc[j].z += wv.x * xv0.z + wv.y * xv1.z + wv.z * xv2.z + wv.w * xv3.z;
                acc[j].w += wv.x * xv0.w + wv.y * xv1.w + wv.z * xv2.w + wv.w * xv3.w;
            }
        }
    }
#pragma unroll
    for (int j = 0; j < 12; ++j) {
        int oc = ocg + j;
        if (oc < 16) {
            *(float4*)&theta[b * 65536 + oc * 4096 + rp * 128 + px4 * 4] = acc[j];
        } else {
            float m0 = fmaxf(acc[j].x, acc[j].y);
            float m1 = fmaxf(acc[j].z, acc[j].w);
            float o0 = fmaxf(m0, __shfl_xor(m0, 16));
            float o1 = fmaxf(m1, __shfl_xor(m1, 16));
            if (px4 < 16) {
                int t = rp * 32 + px4 * 2;
                float2 w2; w2.x = o0; w2.y = o1;
                if (oc < 32) *(float2*)&phi[b * 16384 + (oc - 16) * 1024 + t] = w2;
                else         *(float2*)&g[b * 65536 + (oc - 32) * 1024 + t] = w2;
            }
        }
    }
}

// ------- Kernel C: MFMA fused attention -------------------------------------
// grid: 16 b x 32 s-tiles (128 s each) = 512 blocks, 256 threads (4 waves).
// Per wave: 32 s rows. S = theta^T phi via mfma (K=16 zero-padded to 32).
// PV computed as O^T[s][c] = sum_t P[s][t] g^T[t][c]  (P is the A operand).
// Deferred softmax normalization: divide by L[s] at the end (no max needed,
// |S| <~ 30 so exp() is fp32-safe).
__global__ __launch_bounds__(256) void attn_mfma(
        const float* __restrict__ theta, const float* __restrict__ phi,
        const float* __restrict__ g, float* __restrict__ o) {
    __shared__ unsigned short phT[1024 * 16];   // [t][c] bf16, 32 KB
    __shared__ unsigned short thT[128 * 16];    // [s][c] bf16, 4 KB
    __shared__ unsigned short psT[128 * 72];    // [s][t] bf16, stride 72 (2-way banks, 16B rows)
    __shared__ unsigned short gsT[64 * 72];     // [c][t] bf16, stride 72
    __shared__ float iL[128];
    int tid = threadIdx.x;
    int b = blockIdx.x >> 5, st = blockIdx.x & 31;
    int s0 = st << 7;
    // stage theta tile [s][c]
#pragma unroll
    for (int k = 0; k < 8; ++k) {
        int i = tid + k * 256;
        int c = i >> 7, s = i & 127;
        thT[s * 16 + c] = f2b(theta[b * 65536 + c * 4096 + s0 + s]);
    }
    // stage full phi [t][c]
#pragma unroll
    for (int k = 0; k < 64; ++k) {
        int i = tid + k * 256;
        phT[(i & 1023) * 16 + (i >> 10)] = f2b(phi[b * 16384 + i]);
    }
    __syncthreads();

    int lane = tid & 63, wv = tid >> 6;
    int q = lane >> 4, l = lane & 15;
    int ws = wv * 32;                 // wave's s base within tile
    const bf16x8 zer = {0, 0, 0, 0, 0, 0, 0, 0};
    const f32x4 z4 = {0.f, 0.f, 0.f, 0.f};

    // theta A-frags (persistent): A[m=s=l+16mt][k=c=q*8+j], c>=16 -> 0
    bf16x8 a_th[2];
    a_th[0] = zer; a_th[1] = zer;
    if (q < 2) {
        a_th[0] = *(const bf16x8*)&thT[(ws + l) * 16 + q * 8];
        a_th[1] = *(const bf16x8*)&thT[(ws + 16 + l) * 16 + q * 8];
    }

    f32x4 acc[2][4];                  // O^T accum: [mt(s)][nt(c)]
#pragma unroll
    for (int mt = 0; mt < 2; ++mt)
#pragma unroll
        for (int nt = 0; nt < 4; ++nt) acc[mt][nt] = z4;
    float lp[2][4];                   // per-lane partial row sums
#pragma unroll
    for (int mt = 0; mt < 2; ++mt)
#pragma unroll
        for (int r = 0; r < 4; ++r) lp[mt][r] = 0.f;

    for (int tc = 0; tc < 16; ++tc) {
        int t0 = tc << 6;
        __syncthreads();              // all waves done with previous gsT
        // stage g chunk [c][t] bf16
#pragma unroll
        for (int k = 0; k < 16; ++k) {
            int i = tid + k * 256;
            int c = i >> 6, tl = i & 63;
            gsT[c * 72 + tl] = f2b(g[b * 65536 + c * 1024 + t0 + tl]);
        }
        __syncthreads();
        // S = theta^T phi for this wave's 32 s x 64 t
        f32x4 sacc[2][4];
#pragma unroll
        for (int nt = 0; nt < 4; ++nt) {
            bf16x8 bp = zer;          // B[k=c=q*8+j][n=t=l], c>=16 -> 0
            if (q < 2) bp = *(const bf16x8*)&phT[(t0 + nt * 16 + l) * 16 + q * 8];
            sacc[0][nt] = __builtin_amdgcn_mfma_f32_16x16x32_bf16(a_th[0], bp, z4, 0, 0, 0);
            sacc[1][nt] = __builtin_amdgcn_mfma_f32_16x16x32_bf16(a_th[1], bp, z4, 0, 0, 0);
        }
        // P = exp(S): D layout row(s)=q*4+r, col(t)=l. Accumulate L, stash P
        // into psT[s][t] (wave-private rows; no barrier needed).
#pragma unroll
        for (int mt = 0; mt < 2; ++mt)
#pragma unroll
            for (int nt = 0; nt < 4; ++nt) {
#pragma unroll
                for (int r = 0; r < 4; ++r) {
                    float e = __expf(sacc[mt][nt][r]);
                    lp[mt][r] += e;
                    psT[(ws + mt * 16 + q * 4 + r) * 72 + nt * 16 + l] = f2b(e);
                }
            }
        // PV: O^T[s][c] += P[s][t] gsT[c][t]
#pragma unroll
        for (int kt = 0; kt < 2; ++kt) {
            bf16x8 ap0 = *(const bf16x8*)&psT[(ws + l) * 72 + kt * 32 + q * 8];
            bf16x8 ap1 = *(const bf16x8*)&psT[(ws + 16 + l) * 72 + kt * 32 + q * 8];
#pragma unroll
            for (int nt = 0; nt < 4; ++nt) {
                bf16x8 bg = *(const bf16x8*)&gsT[(nt * 16 + l) * 72 + kt * 32 + q * 8];
                acc[0][nt] = __builtin_amdgcn_mfma_f32_16x16x32_bf16(ap0, bg, acc[0][nt], 0, 0, 0);
                acc[1][nt] = __builtin_amdgcn_mfma_f32_16x16x32_bf16(ap1, bg, acc[1][nt], 0, 0, 0);
            }
        }
    }
    // reduce L across the 16 lanes of each quad, store 1/L
#pragma unroll
    for (int mt = 0; mt < 2; ++mt)
#pragma unroll
        for (int r = 0; r < 4; ++r) {
            float v = lp[mt][r];
            v += __shfl_xor(v, 1);
            v += __shfl_xor(v, 2);
            v += __shfl_xor(v, 4);
            v += __shfl_xor(v, 8);
            if (l == 0) iL[ws + mt * 16 + q * 4 + r] = 1.0f / v;
        }
    // epilogue: normalize + write o[c][s] (64B-line coalesced within wave)
#pragma unroll
    for (int mt = 0; mt < 2; ++mt) {
        f32x4 il4 = *(const f32x4*)&iL[ws + mt * 16 + q * 4];
#pragma unroll
        for (int nt = 0; nt < 4; ++nt) {
            float4 rv;
            rv.x = acc[mt][nt][0] * il4[0];
            rv.y = acc[mt][nt][1] * il4[1];
            rv.z = acc[mt][nt][2] * il4[2];
            rv.w = acc[mt][nt][3] * il4[3];
            *(float4*)&o[b * 262144 + (nt * 16 + l) * 4096 + s0 + ws + mt * 16 + q * 4] = rv;
        }
    }
}

// ------- Kernel D: out = gamma * (Wo @ o) + x --------------------------------
__global__ __launch_bounds__(256) void outconv(
        const float* __restrict__ o, const float* __restrict__ won,
        const float* __restrict__ x, const float* __restrict__ gam,
        float* __restrict__ out) {
    __shared__ float wol[8192];   // [128 oc][64 c]
    __shared__ float ot[4096];    // 32 c x 128 px chunk
    int tid = threadIdx.x;
    int b = blockIdx.x >> 5, pt = blockIdx.x & 31;
    float4* wol4 = (float4*)wol;
    float4* ot4 = (float4*)ot;
    for (int i = tid; i < 2048; i += 256) wol4[i] = ((const float4*)won)[i];
    int px4 = tid & 31, og = (tid >> 5) * 16;
    float4 acc[16];
#pragma unroll
    for (int j = 0; j < 16; ++j) acc[j] = make_float4(0.f, 0.f, 0.f, 0.f);
    for (int cc = 0; cc < 64; cc += 32) {
        __syncthreads();
        for (int k = 0; k < 4; ++k) {
            int f = tid + k * 256;
            int c = f >> 5, p = f & 31;
            ot4[c * 32 + p] = ((const float4*)o)[(b * 64 + cc + c) * 1024 + pt * 32 + p];
        }
        __syncthreads();
#pragma unroll
        for (int c4 = 0; c4 < 8; ++c4) {
            float4 ov0 = ot4[(c4 * 4 + 0) * 32 + px4];
            float4 ov1 = ot4[(c4 * 4 + 1) * 32 + px4];
            float4 ov2 = ot4[(c4 * 4 + 2) * 32 + px4];
            float4 ov3 = ot4[(c4 * 4 + 3) * 32 + px4];
#pragma unroll
            for (int j = 0; j < 16; ++j) {
                float4 wv = wol4[(og + j) * 16 + (cc >> 2) + c4];
                acc[j].x += wv.x * ov0.x + wv.y * ov1.x + wv.z * ov2.x + wv.w * ov3.x;
                acc[j].y += wv.x * ov0.y + wv.y * ov1.y + wv.z * ov2.y + wv.w * ov3.y;
                acc[j].z += wv.x * ov0.z + wv.y * ov1.z + wv.z * ov2.z + wv.w * ov3.z;
                acc[j].w += wv.x * ov0.w + wv.y * ov1.w + wv.z * ov2.w + wv.w * ov3.w;
            }
        }
    }
    float gm = gam[0];
#pragma unroll
    for (int j = 0; j < 16; ++j) {
        int oc = og + j;
        int gi = (b * 128 + oc) * 1024 + pt * 32 + px4;
        float4 xv = ((const float4*)x)[gi];
        float4 r;
        r.x = gm * acc[j].x + xv.x;
        r.y = gm * acc[j].y + xv.y;
        r.z = gm * acc[j].z + xv.z;
        r.w = gm * acc[j].w + xv.w;
        ((float4*)out)[gi] = r;
    }
}

extern "C" void kernel_launch(void* const* d_in, const int* in_sizes, int n_in,
                              void* d_out, int out_size, void* d_ws, size_t ws_size,
                              hipStream_t stream) {
    const float* x  = (const float*)d_in[0];
    const float* wt = (const float*)d_in[1];
    const float* wp = (const float*)d_in[2];
    const float* wg = (const float*)d_in[3];
    const float* wo = (const float*)d_in[4];
    const float* ut = (const float*)d_in[5];
    const float* up = (const float*)d_in[6];
    const float* ug = (const float*)d_in[7];
    const float* uo = (const float*)d_in[8];
    const float* gm = (const float*)d_in[9];
    float* ws = (float*)d_ws;
    float* out = (float*)d_out;

    sn4<<<4, 256, 0, stream>>>(wt, wp, wg, wo, ut, up, ug, uo, ws);
    convpool<<<512, 256, 0, stream>>>(x, ws + WS_WN,
                                      ws + WS_TH, ws + WS_PHI, ws + WS_G);
    attn_mfma<<<512, 256, 0, stream>>>(ws + WS_TH, ws + WS_PHI, ws + WS_G, ws + WS_O);
    outconv<<<512, 256, 0, stream>>>(ws + WS_O, ws + WS_WO, x, gm, out);
}

// Round 3
// 193.973 us; speedup vs baseline: 2.9880x; 1.8373x over previous
//
#include <hip/hip_runtime.h>
#include <hip/hip_bf16.h>

// SAGAN self-attention, B=16, C=128, H=W=64. Inputs fp32, output fp32.
// ws layout in ushorts (bf16):
//   U_WN  = 0        : Wn bf16 [96][128] (theta 0..15, phi 16..31, g 32..95)
//   U_WO  = 12288    : Wo bf16 [128][64]
//   U_TH  = 20480    : thetaT bf16 [16 b][4096 s][16 c]
//   U_PHI = 1069056  : phiT   bf16 [16 b][1024 t][16 c]
//   U_G   = 1331200  : g      bf16 [16 b][64 c][1024 t]
//   U_OT  = 2379776  : oT     bf16 [16 b][4096 s][64 c]
// end 6,574,080 ushort = 13.1 MB.

#define U_WN  0
#define U_WO  12288
#define U_TH  20480
#define U_PHI 1069056
#define U_G   1331200
#define U_OT  2379776

typedef __attribute__((ext_vector_type(8))) short bf16x8;
typedef __attribute__((ext_vector_type(4))) short s16x4;
typedef __attribute__((ext_vector_type(4))) float f32x4;

__device__ inline unsigned short f2b(float f) {
    union { float f; unsigned u; } v; v.f = f;
    unsigned r = v.u + 0x7FFFu + ((v.u >> 16) & 1u);   // RNE
    return (unsigned short)(r >> 16);
}
__device__ inline float b2f(unsigned short u) {
    union { unsigned u; float f; } v; v.u = ((unsigned)u) << 16; return v.f;
}

// ---------------- Kernel A: spectral norm, emit bf16 weights ----------------
__global__ __launch_bounds__(256) void sn4(
        const float* __restrict__ w0, const float* __restrict__ w1,
        const float* __restrict__ w2, const float* __restrict__ w3,
        const float* __restrict__ u0, const float* __restrict__ u1,
        const float* __restrict__ u2, const float* __restrict__ u3,
        unsigned short* __restrict__ wsu) {
    int wi = blockIdx.x;
    const float* W; const float* u; unsigned short* dst; int on, in_;
    if      (wi == 0) { W = w0; u = u0; dst = wsu;          on = 16;  in_ = 128; }
    else if (wi == 1) { W = w1; u = u1; dst = wsu + 2048;   on = 16;  in_ = 128; }
    else if (wi == 2) { W = w2; u = u2; dst = wsu + 4096;   on = 64;  in_ = 128; }
    else              { W = w3; u = u3; dst = wsu + 12288;  on = 128; in_ = 64;  }
    __shared__ float v[128];
    __shared__ float red[256];
    __shared__ float s_inv;
    int tid = threadIdx.x;
    float vi = 0.f;
    if (tid < in_) {
        for (int o = 0; o < on; ++o) vi += u[o] * W[o * in_ + tid];
    }
    red[tid] = (tid < in_) ? vi * vi : 0.f;
    __syncthreads();
    for (int st = 128; st > 0; st >>= 1) {
        if (tid < st) red[tid] += red[tid + st];
        __syncthreads();
    }
    float inv_nv = 1.0f / fmaxf(sqrtf(red[0]), 1e-12f);
    __syncthreads();
    if (tid < in_) v[tid] = vi * inv_nv;
    __syncthreads();
    float ui = 0.f;
    if (tid < on) {
        for (int i = 0; i < in_; ++i) ui += v[i] * W[tid * in_ + i];
    }
    red[tid] = (tid < on) ? ui * ui : 0.f;
    __syncthreads();
    for (int st = 128; st > 0; st >>= 1) {
        if (tid < st) red[tid] += red[tid + st];
        __syncthreads();
    }
    if (tid == 0) {
        float nsq = red[0];
        float sv = nsq / fmaxf(sqrtf(nsq), 1e-12f);
        s_inv = 1.0f / sv;
    }
    __syncthreads();
    float inv = s_inv;
    for (int e = tid; e < on * in_; e += 256) dst[e] = f2b(W[e] * inv);
}

// ------- Kernel B: MFMA conv + 2x2 maxpool ----------------------------------
// grid: 16 b x 32 px-tiles (128 px = 2 image rows) = 512 blocks, 4 waves.
// A = xT[px][c] (LDS micro-transposed bf16), B = Wn[oc][c]. M=128,N=96,K=128.
__global__ __launch_bounds__(256, 2) void convpool_mfma(
        const float* __restrict__ x, const unsigned short* __restrict__ wn,
        unsigned short* __restrict__ thetaT, unsigned short* __restrict__ phiT,
        unsigned short* __restrict__ gT) {
    __shared__ unsigned short xT[128 * 136];   // [px][c], stride 136
    __shared__ unsigned short wnl[96 * 136];   // [oc][c], stride 136; reused as poolbuf
    int tid = threadIdx.x;
    int bb = blockIdx.x >> 5, tile = blockIdx.x & 31;
    int px0 = tile << 7;
    // stage Wn
    for (int i = tid; i < 1536; i += 256) {
        int r = i >> 4, c8 = (i & 15) * 8;
        *(bf16x8*)&wnl[r * 136 + c8] = *(const bf16x8*)&wn[r * 128 + c8];
    }
    // stage xT: 4x4 register micro-transpose, 8B LDS writes
    const float4* x4 = (const float4*)x;
    {
        int p4 = tid & 31, cg = (tid >> 5) * 4;
        for (int k = 0; k < 4; ++k) {
            int cb = k * 32 + cg;
            float4 v0 = x4[(bb * 128 + cb + 0) * 1024 + tile * 32 + p4];
            float4 v1 = x4[(bb * 128 + cb + 1) * 1024 + tile * 32 + p4];
            float4 v2 = x4[(bb * 128 + cb + 2) * 1024 + tile * 32 + p4];
            float4 v3 = x4[(bb * 128 + cb + 3) * 1024 + tile * 32 + p4];
            float a0[4] = {v0.x, v0.y, v0.z, v0.w};
            float a1[4] = {v1.x, v1.y, v1.z, v1.w};
            float a2[4] = {v2.x, v2.y, v2.z, v2.w};
            float a3[4] = {v3.x, v3.y, v3.z, v3.w};
#pragma unroll
            for (int j = 0; j < 4; ++j) {
                s16x4 u; u[0] = (short)f2b(a0[j]); u[1] = (short)f2b(a1[j]);
                u[2] = (short)f2b(a2[j]); u[3] = (short)f2b(a3[j]);
                *(s16x4*)&xT[(p4 * 4 + j) * 136 + cb] = u;
            }
        }
    }
    __syncthreads();
    int lane = tid & 63, wv = tid >> 6;
    int q = lane >> 4, l = lane & 15;
    int pxw = wv * 32;
    f32x4 acc[2][6];
    const f32x4 z4 = {0.f, 0.f, 0.f, 0.f};
#pragma unroll
    for (int mt = 0; mt < 2; ++mt)
#pragma unroll
        for (int nt = 0; nt < 6; ++nt) acc[mt][nt] = z4;
#pragma unroll
    for (int kk = 0; kk < 4; ++kk) {
        bf16x8 a0 = *(const bf16x8*)&xT[(pxw + l) * 136 + kk * 32 + q * 8];
        bf16x8 a1 = *(const bf16x8*)&xT[(pxw + 16 + l) * 136 + kk * 32 + q * 8];
#pragma unroll
        for (int nt = 0; nt < 6; ++nt) {
            bf16x8 bw = *(const bf16x8*)&wnl[(nt * 16 + l) * 136 + kk * 32 + q * 8];
            acc[0][nt] = __builtin_amdgcn_mfma_f32_16x16x32_bf16(a0, bw, acc[0][nt], 0, 0, 0);
            acc[1][nt] = __builtin_amdgcn_mfma_f32_16x16x32_bf16(a1, bw, acc[1][nt], 0, 0, 0);
        }
    }
    // theta (nt=0): write thetaT[s][c], c=l
#pragma unroll
    for (int mt = 0; mt < 2; ++mt)
#pragma unroll
        for (int r = 0; r < 4; ++r) {
            int s = px0 + pxw + mt * 16 + q * 4 + r;
            thetaT[(bb * 4096 + s) * 16 + l] = f2b(acc[mt][0][r]);
        }
    __syncthreads();   // all waves done reading wnl
    unsigned short* poolbuf = wnl;   // [80 ch][px] stride 132
#pragma unroll
    for (int mt = 0; mt < 2; ++mt)
#pragma unroll
        for (int nt = 1; nt < 6; ++nt) {
            int ch = nt * 16 + l - 16;
#pragma unroll
            for (int r = 0; r < 4; ++r) {
                poolbuf[ch * 132 + pxw + mt * 16 + q * 4 + r] = f2b(acc[mt][nt][r]);
            }
        }
    __syncthreads();
    // 2x2 maxpool: block covers image rows 2*tile, 2*tile+1 -> pooled row = tile
    for (int i = tid; i < 2560; i += 256) {
        int tcol = i & 31, ch = i >> 5;
        int base = ch * 132 + tcol * 2;
        float m0 = fmaxf(b2f(poolbuf[base]), b2f(poolbuf[base + 1]));
        float m1 = fmaxf(b2f(poolbuf[base + 64]), b2f(poolbuf[base + 65]));
        float m = fmaxf(m0, m1);
        int t = tile * 32 + tcol;
        if (ch < 16) phiT[(bb * 1024 + t) * 16 + ch] = f2b(m);
        else         gT[(bb * 64 + ch - 16) * 1024 + t] = f2b(m);
    }
}

// ------- Kernel C: MFMA fused attention -------------------------------------
// grid: 16 b x 32 s-tiles (128 s) = 512 blocks, 4 waves x 32 s.
__global__ __launch_bounds__(256) void attn_mfma(
        const unsigned short* __restrict__ thetaT,
        const unsigned short* __restrict__ phiT,
        const unsigned short* __restrict__ gT,
        unsigned short* __restrict__ oT) {
    __shared__ unsigned short phT[1024 * 16];   // [t][c] bf16
    __shared__ unsigned short psT[128 * 72];    // [s][t] bf16; reused for oT bounce
    __shared__ unsigned short gsT[64 * 72];     // [c][t] bf16
    int tid = threadIdx.x;
    int bb = blockIdx.x >> 5, st = blockIdx.x & 31;
    int s0 = st << 7;
    // stage full phi [t][c]
    for (int i = tid; i < 2048; i += 256) {
        *(bf16x8*)&phT[i * 8] = *(const bf16x8*)&phiT[bb * 16384 + i * 8];
    }
    int lane = tid & 63, wv = tid >> 6;
    int q = lane >> 4, l = lane & 15;
    int wsb = wv * 32;
    const bf16x8 zer = {0, 0, 0, 0, 0, 0, 0, 0};
    const f32x4 z4 = {0.f, 0.f, 0.f, 0.f};
    // theta A-frags direct from global (K=16 zero-padded to 32)
    bf16x8 a_th[2];
    a_th[0] = zer; a_th[1] = zer;
    if (q < 2) {
        a_th[0] = *(const bf16x8*)&thetaT[(bb * 4096 + s0 + wsb + l) * 16 + q * 8];
        a_th[1] = *(const bf16x8*)&thetaT[(bb * 4096 + s0 + wsb + 16 + l) * 16 + q * 8];
    }
    __syncthreads();

    f32x4 acc[2][4];
#pragma unroll
    for (int mt = 0; mt < 2; ++mt)
#pragma unroll
        for (int nt = 0; nt < 4; ++nt) acc[mt][nt] = z4;
    float lp[2][4];
#pragma unroll
    for (int mt = 0; mt < 2; ++mt)
#pragma unroll
        for (int r = 0; r < 4; ++r) lp[mt][r] = 0.f;

    for (int tc = 0; tc < 16; ++tc) {
        int t0 = tc << 6;
        __syncthreads();
        // stage g chunk [c][t]
        for (int i = tid; i < 512; i += 256) {
            int c = i >> 3, t8 = (i & 7) * 8;
            *(bf16x8*)&gsT[c * 72 + t8] = *(const bf16x8*)&gT[(bb * 64 + c) * 1024 + t0 + t8];
        }
        __syncthreads();
        // S = theta^T phi
        f32x4 sacc[2][4];
#pragma unroll
        for (int nt = 0; nt < 4; ++nt) {
            bf16x8 bp = zer;
            if (q < 2) bp = *(const bf16x8*)&phT[(t0 + nt * 16 + l) * 16 + q * 8];
            sacc[0][nt] = __builtin_amdgcn_mfma_f32_16x16x32_bf16(a_th[0], bp, z4, 0, 0, 0);
            sacc[1][nt] = __builtin_amdgcn_mfma_f32_16x16x32_bf16(a_th[1], bp, z4, 0, 0, 0);
        }
        // P = exp(S) -> psT (wave-private rows)
#pragma unroll
        for (int mt = 0; mt < 2; ++mt)
#pragma unroll
            for (int nt = 0; nt < 4; ++nt) {
#pragma unroll
                for (int r = 0; r < 4; ++r) {
                    float e = __expf(sacc[mt][nt][r]);
                    lp[mt][r] += e;
                    psT[(wsb + mt * 16 + q * 4 + r) * 72 + nt * 16 + l] = f2b(e);
                }
            }
        // PV: O^T[s][c] += P[s][t] g[c][t]
#pragma unroll
        for (int kt = 0; kt < 2; ++kt) {
            bf16x8 ap0 = *(const bf16x8*)&psT[(wsb + l) * 72 + kt * 32 + q * 8];
            bf16x8 ap1 = *(const bf16x8*)&psT[(wsb + 16 + l) * 72 + kt * 32 + q * 8];
#pragma unroll
            for (int nt = 0; nt < 4; ++nt) {
                bf16x8 bg = *(const bf16x8*)&gsT[(nt * 16 + l) * 72 + kt * 32 + q * 8];
                acc[0][nt] = __builtin_amdgcn_mfma_f32_16x16x32_bf16(ap0, bg, acc[0][nt], 0, 0, 0);
                acc[1][nt] = __builtin_amdgcn_mfma_f32_16x16x32_bf16(ap1, bg, acc[1][nt], 0, 0, 0);
            }
        }
    }
    // per-row softmax denominators via butterfly (all lanes get the sum)
    float inv[2][4];
#pragma unroll
    for (int mt = 0; mt < 2; ++mt)
#pragma unroll
        for (int r = 0; r < 4; ++r) {
            float v = lp[mt][r];
            v += __shfl_xor(v, 1);
            v += __shfl_xor(v, 2);
            v += __shfl_xor(v, 4);
            v += __shfl_xor(v, 8);
            inv[mt][r] = 1.0f / v;
        }
    // dump normalized O^T into psT [s][c], then coalesced bf16 global write
#pragma unroll
    for (int mt = 0; mt < 2; ++mt)
#pragma unroll
        for (int nt = 0; nt < 4; ++nt)
#pragma unroll
            for (int r = 0; r < 4; ++r)
                psT[(wsb + mt * 16 + q * 4 + r) * 72 + nt * 16 + l] =
                    f2b(acc[mt][nt][r] * inv[mt][r]);
    __syncthreads();
    for (int i = tid; i < 1024; i += 256) {
        int s = i >> 3, c8 = (i & 7) * 8;
        *(bf16x8*)&oT[(bb * 4096 + s0 + s) * 64 + c8] = *(const bf16x8*)&psT[s * 72 + c8];
    }
}

// ------- Kernel D: out = gamma * (Wo @ o) + x  (MFMA) -----------------------
// grid: 16 b x 16 px-tiles (256 px) = 256 blocks, 4 waves x 64 px.
// A = oT[px][c] direct from global, B = Wo[oc][c] in LDS. M=256,N=128,K=64.
__global__ __launch_bounds__(256, 2) void outconv_mfma(
        const unsigned short* __restrict__ oT, const unsigned short* __restrict__ wo,
        const float* __restrict__ x, const float* __restrict__ gam,
        float* __restrict__ out) {
    __shared__ unsigned short wol[128 * 72];   // [oc][c] stride 72
    int tid = threadIdx.x;
    int bb = blockIdx.x >> 4, tile = blockIdx.x & 15;
    int lane = tid & 63, wv = tid >> 6;
    int q = lane >> 4, l = lane & 15;
    int pxw = tile * 256 + wv * 64;
    for (int i = tid; i < 1024; i += 256) {
        int r = i >> 3, c8 = (i & 7) * 8;
        *(bf16x8*)&wol[r * 72 + c8] = *(const bf16x8*)&wo[r * 64 + c8];
    }
    // A-frags: 4 m-tiles x 2 k-steps
    bf16x8 af[4][2];
#pragma unroll
    for (int mt = 0; mt < 4; ++mt)
#pragma unroll
        for (int kk = 0; kk < 2; ++kk)
            af[mt][kk] = *(const bf16x8*)&oT[(bb * 4096 + pxw + mt * 16 + l) * 64 + kk * 32 + q * 8];
    __syncthreads();
    f32x4 acc[4][8];
    const f32x4 z4 = {0.f, 0.f, 0.f, 0.f};
#pragma unroll
    for (int mt = 0; mt < 4; ++mt)
#pragma unroll
        for (int nt = 0; nt < 8; ++nt) acc[mt][nt] = z4;
#pragma unroll
    for (int kk = 0; kk < 2; ++kk) {
#pragma unroll
        for (int nt = 0; nt < 8; ++nt) {
            bf16x8 bw = *(const bf16x8*)&wol[(nt * 16 + l) * 72 + kk * 32 + q * 8];
#pragma unroll
            for (int mt = 0; mt < 4; ++mt)
                acc[mt][nt] = __builtin_amdgcn_mfma_f32_16x16x32_bf16(af[mt][kk], bw, acc[mt][nt], 0, 0, 0);
        }
    }
    float gm = gam[0];
    const float4* x4 = (const float4*)x;
    float4* out4 = (float4*)out;
#pragma unroll
    for (int mt = 0; mt < 4; ++mt)
#pragma unroll
        for (int nt = 0; nt < 8; ++nt) {
            int oc = nt * 16 + l;
            int px = pxw + mt * 16 + q * 4;
            int gi = (bb * 128 + oc) * 1024 + (px >> 2);
            float4 xv = x4[gi];
            float4 r;
            r.x = gm * acc[mt][nt][0] + xv.x;
            r.y = gm * acc[mt][nt][1] + xv.y;
            r.z = gm * acc[mt][nt][2] + xv.z;
            r.w = gm * acc[mt][nt][3] + xv.w;
            out4[gi] = r;
        }
}

extern "C" void kernel_launch(void* const* d_in, const int* in_sizes, int n_in,
                              void* d_out, int out_size, void* d_ws, size_t ws_size,
                              hipStream_t stream) {
    const float* x  = (const float*)d_in[0];
    const float* wt = (const float*)d_in[1];
    const float* wp = (const float*)d_in[2];
    const float* wg = (const float*)d_in[3];
    const float* wo = (const float*)d_in[4];
    const float* ut = (const float*)d_in[5];
    const float* up = (const float*)d_in[6];
    const float* ug = (const float*)d_in[7];
    const float* uo = (const float*)d_in[8];
    const float* gm = (const float*)d_in[9];
    unsigned short* wsu = (unsigned short*)d_ws;
    float* out = (float*)d_out;

    sn4<<<4, 256, 0, stream>>>(wt, wp, wg, wo, ut, up, ug, uo, wsu);
    convpool_mfma<<<512, 256, 0, stream>>>(x, wsu + U_WN,
                                           wsu + U_TH, wsu + U_PHI, wsu + U_G);
    attn_mfma<<<512, 256, 0, stream>>>(wsu + U_TH, wsu + U_PHI, wsu + U_G, wsu + U_OT);
    outconv_mfma<<<256, 256, 0, stream>>>(wsu + U_OT, wsu + U_WO, x, gm, out);
}

// Round 4
// 164.822 us; speedup vs baseline: 3.5165x; 1.1769x over previous
//
#include <hip/hip_runtime.h>
#include <hip/hip_bf16.h>

// SAGAN self-attention, B=16, C=128, H=W=64. Inputs fp32, output fp32.
// ws layout in ushorts (bf16):
//   U_WN  = 0        : Wn bf16 [96][128] (theta 0..15, phi 16..31, g 32..95)
//   U_WO  = 12288    : Wo bf16 [128][64]
//   U_TH  = 20480    : thetaT bf16 [16 b][4096 s][16 c]
//   U_PHI = 1069056  : phiT   bf16 [16 b][1024 t][16 c]
//   U_G   = 1331200  : g      bf16 [16 b][64 c][1024 t]
//   U_OT  = 2379776  : oT     bf16 [16 b][4096 s][64 c]

#define U_WN  0
#define U_WO  12288
#define U_TH  20480
#define U_PHI 1069056
#define U_G   1331200
#define U_OT  2379776

typedef __attribute__((ext_vector_type(8))) short bf16x8;
typedef __attribute__((ext_vector_type(4))) short s16x4;
typedef __attribute__((ext_vector_type(4))) float f32x4;

__device__ inline unsigned short f2b(float f) {
    union { float f; unsigned u; } v; v.f = f;
    unsigned r = v.u + 0x7FFFu + ((v.u >> 16) & 1u);   // RNE
    return (unsigned short)(r >> 16);
}
__device__ inline float b2f(unsigned short u) {
    union { unsigned u; float f; } v; v.u = ((unsigned)u) << 16; return v.f;
}

// ---------------- Kernel A: spectral norm, emit bf16 weights ----------------
// W staged in LDS (coalesced, padded stride) so the power-iteration matvecs
// run at LDS latency, not serial cold-HBM latency (was 55 us: 4 blocks,
// non-pipelined dependent global loads).
__global__ __launch_bounds__(256) void sn4(
        const float* __restrict__ w0, const float* __restrict__ w1,
        const float* __restrict__ w2, const float* __restrict__ w3,
        const float* __restrict__ u0, const float* __restrict__ u1,
        const float* __restrict__ u2, const float* __restrict__ u3,
        unsigned short* __restrict__ wsu) {
    int wi = blockIdx.x;
    const float* W; const float* u; unsigned short* dst; int on, in_;
    if      (wi == 0) { W = w0; u = u0; dst = wsu;          on = 16;  in_ = 128; }
    else if (wi == 1) { W = w1; u = u1; dst = wsu + 2048;   on = 16;  in_ = 128; }
    else if (wi == 2) { W = w2; u = u2; dst = wsu + 4096;   on = 64;  in_ = 128; }
    else              { W = w3; u = u3; dst = wsu + 12288;  on = 128; in_ = 64;  }
    __shared__ float Wl[8320];    // [on][in_+1], max(128*65, 64*129) = 8320
    __shared__ float ul[128];
    __shared__ float v[128];
    __shared__ float red[256];
    __shared__ float s_inv;
    int tid = threadIdx.x;
    int n = on * in_;
    int stride = in_ + 1;
    int shift = (in_ == 128) ? 7 : 6;
    int mask = in_ - 1;
    // stage W -> LDS, coalesced independent loads (one round trip)
    for (int i = tid; i < n; i += 256) {
        int o = i >> shift, j = i & mask;
        Wl[o * stride + j] = W[i];
    }
    if (tid < on) ul[tid] = u[tid];
    __syncthreads();
    // v_raw = u @ W  (columns across lanes: bank-clean)
    float vi = 0.f;
    if (tid < in_) {
        for (int o = 0; o < on; ++o) vi += ul[o] * Wl[o * stride + tid];
    }
    red[tid] = (tid < in_) ? vi * vi : 0.f;
    __syncthreads();
    for (int st = 128; st > 0; st >>= 1) {
        if (tid < st) red[tid] += red[tid + st];
        __syncthreads();
    }
    float inv_nv = 1.0f / fmaxf(sqrtf(red[0]), 1e-12f);
    __syncthreads();
    if (tid < in_) v[tid] = vi * inv_nv;
    __syncthreads();
    // u2_raw = v @ W^T  (rows per lane: padded stride -> bank-clean)
    float ui = 0.f;
    if (tid < on) {
        for (int i = 0; i < in_; ++i) ui += v[i] * Wl[tid * stride + i];
    }
    red[tid] = (tid < on) ? ui * ui : 0.f;
    __syncthreads();
    for (int st = 128; st > 0; st >>= 1) {
        if (tid < st) red[tid] += red[tid + st];
        __syncthreads();
    }
    if (tid == 0) {
        float nsq = red[0];
        float sv = nsq / fmaxf(sqrtf(nsq), 1e-12f);
        s_inv = 1.0f / sv;
    }
    __syncthreads();
    float inv = s_inv;
    for (int e = tid; e < n; e += 256) {
        int o = e >> shift, j = e & mask;
        dst[e] = f2b(Wl[o * stride + j] * inv);
    }
}

// ------- Kernel B: MFMA conv + 2x2 maxpool ----------------------------------
// grid: 16 b x 32 px-tiles (128 px = 2 image rows) = 512 blocks, 4 waves.
// A = xT[px][c] (LDS micro-transposed bf16), B = Wn[oc][c]. M=128,N=96,K=128.
__global__ __launch_bounds__(256, 2) void convpool_mfma(
        const float* __restrict__ x, const unsigned short* __restrict__ wn,
        unsigned short* __restrict__ thetaT, unsigned short* __restrict__ phiT,
        unsigned short* __restrict__ gT) {
    __shared__ unsigned short xT[128 * 136];   // [px][c], stride 136
    __shared__ unsigned short wnl[96 * 136];   // [oc][c], stride 136; reused as poolbuf
    int tid = threadIdx.x;
    int bb = blockIdx.x >> 5, tile = blockIdx.x & 31;
    int px0 = tile << 7;
    // stage Wn
    for (int i = tid; i < 1536; i += 256) {
        int r = i >> 4, c8 = (i & 15) * 8;
        *(bf16x8*)&wnl[r * 136 + c8] = *(const bf16x8*)&wn[r * 128 + c8];
    }
    // stage xT: 4x4 register micro-transpose, 8B LDS writes
    const float4* x4 = (const float4*)x;
    {
        int p4 = tid & 31, cg = (tid >> 5) * 4;
        for (int k = 0; k < 4; ++k) {
            int cb = k * 32 + cg;
            float4 v0 = x4[(bb * 128 + cb + 0) * 1024 + tile * 32 + p4];
            float4 v1 = x4[(bb * 128 + cb + 1) * 1024 + tile * 32 + p4];
            float4 v2 = x4[(bb * 128 + cb + 2) * 1024 + tile * 32 + p4];
            float4 v3 = x4[(bb * 128 + cb + 3) * 1024 + tile * 32 + p4];
            float a0[4] = {v0.x, v0.y, v0.z, v0.w};
            float a1[4] = {v1.x, v1.y, v1.z, v1.w};
            float a2[4] = {v2.x, v2.y, v2.z, v2.w};
            float a3[4] = {v3.x, v3.y, v3.z, v3.w};
#pragma unroll
            for (int j = 0; j < 4; ++j) {
                s16x4 u; u[0] = (short)f2b(a0[j]); u[1] = (short)f2b(a1[j]);
                u[2] = (short)f2b(a2[j]); u[3] = (short)f2b(a3[j]);
                *(s16x4*)&xT[(p4 * 4 + j) * 136 + cb] = u;
            }
        }
    }
    __syncthreads();
    int lane = tid & 63, wv = tid >> 6;
    int q = lane >> 4, l = lane & 15;
    int pxw = wv * 32;
    f32x4 acc[2][6];
    const f32x4 z4 = {0.f, 0.f, 0.f, 0.f};
#pragma unroll
    for (int mt = 0; mt < 2; ++mt)
#pragma unroll
        for (int nt = 0; nt < 6; ++nt) acc[mt][nt] = z4;
#pragma unroll
    for (int kk = 0; kk < 4; ++kk) {
        bf16x8 a0 = *(const bf16x8*)&xT[(pxw + l) * 136 + kk * 32 + q * 8];
        bf16x8 a1 = *(const bf16x8*)&xT[(pxw + 16 + l) * 136 + kk * 32 + q * 8];
#pragma unroll
        for (int nt = 0; nt < 6; ++nt) {
            bf16x8 bw = *(const bf16x8*)&wnl[(nt * 16 + l) * 136 + kk * 32 + q * 8];
            acc[0][nt] = __builtin_amdgcn_mfma_f32_16x16x32_bf16(a0, bw, acc[0][nt], 0, 0, 0);
            acc[1][nt] = __builtin_amdgcn_mfma_f32_16x16x32_bf16(a1, bw, acc[1][nt], 0, 0, 0);
        }
    }
    // theta (nt=0): write thetaT[s][c], c=l
#pragma unroll
    for (int mt = 0; mt < 2; ++mt)
#pragma unroll
        for (int r = 0; r < 4; ++r) {
            int s = px0 + pxw + mt * 16 + q * 4 + r;
            thetaT[(bb * 4096 + s) * 16 + l] = f2b(acc[mt][0][r]);
        }
    __syncthreads();   // all waves done reading wnl
    unsigned short* poolbuf = wnl;   // [80 ch][px] stride 132
#pragma unroll
    for (int mt = 0; mt < 2; ++mt)
#pragma unroll
        for (int nt = 1; nt < 6; ++nt) {
            int ch = nt * 16 + l - 16;
#pragma unroll
            for (int r = 0; r < 4; ++r) {
                poolbuf[ch * 132 + pxw + mt * 16 + q * 4 + r] = f2b(acc[mt][nt][r]);
            }
        }
    __syncthreads();
    // 2x2 maxpool: block covers image rows 2*tile, 2*tile+1 -> pooled row = tile
    for (int i = tid; i < 2560; i += 256) {
        int tcol = i & 31, ch = i >> 5;
        int base = ch * 132 + tcol * 2;
        float m0 = fmaxf(b2f(poolbuf[base]), b2f(poolbuf[base + 1]));
        float m1 = fmaxf(b2f(poolbuf[base + 64]), b2f(poolbuf[base + 65]));
        float m = fmaxf(m0, m1);
        int t = tile * 32 + tcol;
        if (ch < 16) phiT[(bb * 1024 + t) * 16 + ch] = f2b(m);
        else         gT[(bb * 64 + ch - 16) * 1024 + t] = f2b(m);
    }
}

// ------- Kernel C: MFMA fused attention -------------------------------------
// grid: 16 b x 32 s-tiles (128 s) = 512 blocks, 4 waves x 32 s.
__global__ __launch_bounds__(256) void attn_mfma(
        const unsigned short* __restrict__ thetaT,
        const unsigned short* __restrict__ phiT,
        const unsigned short* __restrict__ gT,
        unsigned short* __restrict__ oT) {
    __shared__ unsigned short phT[1024 * 16];   // [t][c] bf16
    __shared__ unsigned short psT[128 * 72];    // [s][t] bf16; reused for oT bounce
    __shared__ unsigned short gsT[64 * 72];     // [c][t] bf16
    int tid = threadIdx.x;
    int bb = blockIdx.x >> 5, st = blockIdx.x & 31;
    int s0 = st << 7;
    // stage full phi [t][c]
    for (int i = tid; i < 2048; i += 256) {
        *(bf16x8*)&phT[i * 8] = *(const bf16x8*)&phiT[bb * 16384 + i * 8];
    }
    int lane = tid & 63, wv = tid >> 6;
    int q = lane >> 4, l = lane & 15;
    int wsb = wv * 32;
    const bf16x8 zer = {0, 0, 0, 0, 0, 0, 0, 0};
    const f32x4 z4 = {0.f, 0.f, 0.f, 0.f};
    // theta A-frags direct from global (K=16 zero-padded to 32)
    bf16x8 a_th[2];
    a_th[0] = zer; a_th[1] = zer;
    if (q < 2) {
        a_th[0] = *(const bf16x8*)&thetaT[(bb * 4096 + s0 + wsb + l) * 16 + q * 8];
        a_th[1] = *(const bf16x8*)&thetaT[(bb * 4096 + s0 + wsb + 16 + l) * 16 + q * 8];
    }
    __syncthreads();

    f32x4 acc[2][4];
#pragma unroll
    for (int mt = 0; mt < 2; ++mt)
#pragma unroll
        for (int nt = 0; nt < 4; ++nt) acc[mt][nt] = z4;
    float lp[2][4];
#pragma unroll
    for (int mt = 0; mt < 2; ++mt)
#pragma unroll
        for (int r = 0; r < 4; ++r) lp[mt][r] = 0.f;

    for (int tc = 0; tc < 16; ++tc) {
        int t0 = tc << 6;
        __syncthreads();
        // stage g chunk [c][t]
        for (int i = tid; i < 512; i += 256) {
            int c = i >> 3, t8 = (i & 7) * 8;
            *(bf16x8*)&gsT[c * 72 + t8] = *(const bf16x8*)&gT[(bb * 64 + c) * 1024 + t0 + t8];
        }
        __syncthreads();
        // S = theta^T phi
        f32x4 sacc[2][4];
#pragma unroll
        for (int nt = 0; nt < 4; ++nt) {
            bf16x8 bp = zer;
            if (q < 2) bp = *(const bf16x8*)&phT[(t0 + nt * 16 + l) * 16 + q * 8];
            sacc[0][nt] = __builtin_amdgcn_mfma_f32_16x16x32_bf16(a_th[0], bp, z4, 0, 0, 0);
            sacc[1][nt] = __builtin_amdgcn_mfma_f32_16x16x32_bf16(a_th[1], bp, z4, 0, 0, 0);
        }
        // P = exp(S) -> psT (wave-private rows)
#pragma unroll
        for (int mt = 0; mt < 2; ++mt)
#pragma unroll
            for (int nt = 0; nt < 4; ++nt) {
#pragma unroll
                for (int r = 0; r < 4; ++r) {
                    float e = __expf(sacc[mt][nt][r]);
                    lp[mt][r] += e;
                    psT[(wsb + mt * 16 + q * 4 + r) * 72 + nt * 16 + l] = f2b(e);
                }
            }
        // PV: O^T[s][c] += P[s][t] g[c][t]
#pragma unroll
        for (int kt = 0; kt < 2; ++kt) {
            bf16x8 ap0 = *(const bf16x8*)&psT[(wsb + l) * 72 + kt * 32 + q * 8];
            bf16x8 ap1 = *(const bf16x8*)&psT[(wsb + 16 + l) * 72 + kt * 32 + q * 8];
#pragma unroll
            for (int nt = 0; nt < 4; ++nt) {
                bf16x8 bg = *(const bf16x8*)&gsT[(nt * 16 + l) * 72 + kt * 32 + q * 8];
                acc[0][nt] = __builtin_amdgcn_mfma_f32_16x16x32_bf16(ap0, bg, acc[0][nt], 0, 0, 0);
                acc[1][nt] = __builtin_amdgcn_mfma_f32_16x16x32_bf16(ap1, bg, acc[1][nt], 0, 0, 0);
            }
        }
    }
    // per-row softmax denominators via butterfly (all lanes get the sum)
    float inv[2][4];
#pragma unroll
    for (int mt = 0; mt < 2; ++mt)
#pragma unroll
        for (int r = 0; r < 4; ++r) {
            float v = lp[mt][r];
            v += __shfl_xor(v, 1);
            v += __shfl_xor(v, 2);
            v += __shfl_xor(v, 4);
            v += __shfl_xor(v, 8);
            inv[mt][r] = 1.0f / v;
        }
    // dump normalized O^T into psT [s][c], then coalesced bf16 global write
#pragma unroll
    for (int mt = 0; mt < 2; ++mt)
#pragma unroll
        for (int nt = 0; nt < 4; ++nt)
#pragma unroll
            for (int r = 0; r < 4; ++r)
                psT[(wsb + mt * 16 + q * 4 + r) * 72 + nt * 16 + l] =
                    f2b(acc[mt][nt][r] * inv[mt][r]);
    __syncthreads();
    for (int i = tid; i < 1024; i += 256) {
        int s = i >> 3, c8 = (i & 7) * 8;
        *(bf16x8*)&oT[(bb * 4096 + s0 + s) * 64 + c8] = *(const bf16x8*)&psT[s * 72 + c8];
    }
}

// ------- Kernel D: out = gamma * (Wo @ o) + x  (MFMA) -----------------------
// grid: 16 b x 16 px-tiles (256 px) = 256 blocks, 4 waves x 64 px.
__global__ __launch_bounds__(256, 2) void outconv_mfma(
        const unsigned short* __restrict__ oT, const unsigned short* __restrict__ wo,
        const float* __restrict__ x, const float* __restrict__ gam,
        float* __restrict__ out) {
    __shared__ unsigned short wol[128 * 72];   // [oc][c] stride 72
    int tid = threadIdx.x;
    int bb = blockIdx.x >> 4, tile = blockIdx.x & 15;
    int lane = tid & 63, wv = tid >> 6;
    int q = lane >> 4, l = lane & 15;
    int pxw = tile * 256 + wv * 64;
    for (int i = tid; i < 1024; i += 256) {
        int r = i >> 3, c8 = (i & 7) * 8;
        *(bf16x8*)&wol[r * 72 + c8] = *(const bf16x8*)&wo[r * 64 + c8];
    }
    // A-frags: 4 m-tiles x 2 k-steps
    bf16x8 af[4][2];
#pragma unroll
    for (int mt = 0; mt < 4; ++mt)
#pragma unroll
        for (int kk = 0; kk < 2; ++kk)
            af[mt][kk] = *(const bf16x8*)&oT[(bb * 4096 + pxw + mt * 16 + l) * 64 + kk * 32 + q * 8];
    __syncthreads();
    f32x4 acc[4][8];
    const f32x4 z4 = {0.f, 0.f, 0.f, 0.f};
#pragma unroll
    for (int mt = 0; mt < 4; ++mt)
#pragma unroll
        for (int nt = 0; nt < 8; ++nt) acc[mt][nt] = z4;
#pragma unroll
    for (int kk = 0; kk < 2; ++kk) {
#pragma unroll
        for (int nt = 0; nt < 8; ++nt) {
            bf16x8 bw = *(const bf16x8*)&wol[(nt * 16 + l) * 72 + kk * 32 + q * 8];
#pragma unroll
            for (int mt = 0; mt < 4; ++mt)
                acc[mt][nt] = __builtin_amdgcn_mfma_f32_16x16x32_bf16(af[mt][kk], bw, acc[mt][nt], 0, 0, 0);
        }
    }
    float gm = gam[0];
    const float4* x4 = (const float4*)x;
    float4* out4 = (float4*)out;
#pragma unroll
    for (int mt = 0; mt < 4; ++mt)
#pragma unroll
        for (int nt = 0; nt < 8; ++nt) {
            int oc = nt * 16 + l;
            int px = pxw + mt * 16 + q * 4;
            int gi = (bb * 128 + oc) * 1024 + (px >> 2);
            float4 xv = x4[gi];
            float4 r;
            r.x = gm * acc[mt][nt][0] + xv.x;
            r.y = gm * acc[mt][nt][1] + xv.y;
            r.z = gm * acc[mt][nt][2] + xv.z;
            r.w = gm * acc[mt][nt][3] + xv.w;
            out4[gi] = r;
        }
}

extern "C" void kernel_launch(void* const* d_in, const int* in_sizes, int n_in,
                              void* d_out, int out_size, void* d_ws, size_t ws_size,
                              hipStream_t stream) {
    const float* x  = (const float*)d_in[0];
    const float* wt = (const float*)d_in[1];
    const float* wp = (const float*)d_in[2];
    const float* wg = (const float*)d_in[3];
    const float* wo = (const float*)d_in[4];
    const float* ut = (const float*)d_in[5];
    const float* up = (const float*)d_in[6];
    const float* ug = (const float*)d_in[7];
    const float* uo = (const float*)d_in[8];
    const float* gm = (const float*)d_in[9];
    unsigned short* wsu = (unsigned short*)d_ws;
    float* out = (float*)d_out;

    sn4<<<4, 256, 0, stream>>>(wt, wp, wg, wo, ut, up, ug, uo, wsu);
    convpool_mfma<<<512, 256, 0, stream>>>(x, wsu + U_WN,
                                           wsu + U_TH, wsu + U_PHI, wsu + U_G);
    attn_mfma<<<512, 256, 0, stream>>>(wsu + U_TH, wsu + U_PHI, wsu + U_G, wsu + U_OT);
    outconv_mfma<<<256, 256, 0, stream>>>(wsu + U_OT, wsu + U_WO, x, gm, out);
}